// Round 3
// baseline (318.254 us; speedup 1.0000x reference)
//
#include <hip/hip_runtime.h>
#include <hip/hip_bf16.h>
#include <cstdint>
#include <cstddef>

// Problem constants: T=1024, H=1024, I=512, E=16, K=4
#define T_TOK 1024
#define HDIM  1024
#define IDIM  512
#define NEXP  16
#define TOPK  4
#define CAP   1024   // per-expert entry capacity (mean 256, sd ~15.5)

typedef __bf16 bf16;
typedef __attribute__((ext_vector_type(8))) __bf16 bf16x8;
typedef __attribute__((ext_vector_type(4))) __bf16 bf16x4;
typedef __attribute__((ext_vector_type(4))) float f32x4;

__device__ __forceinline__ void lds_load16(void* lds_dst, const void* g_src) {
  __builtin_amdgcn_global_load_lds(
      (__attribute__((address_space(1))) unsigned int*)(void*)(g_src),
      (__attribute__((address_space(3))) unsigned int*)(lds_dst),
      16, 0, 0);
}

__device__ __forceinline__ bf16x8 pack2(float4 a, float4 b) {
  bf16x8 o;
  o[0] = (bf16)a.x; o[1] = (bf16)a.y; o[2] = (bf16)a.z; o[3] = (bf16)a.w;
  o[4] = (bf16)b.x; o[5] = (bf16)b.y; o[6] = (bf16)b.z; o[7] = (bf16)b.w;
  return o;
}

// ---------------- prep ----------------

// One block, 1024 threads: scatter (t,k) -> per-expert lists, pad to x64.
// Entry payload: packed (t<<2)|k. Pads: (T_TOK<<2) -> gather row T (zeros),
// scatter to slab0 trash row T.
__global__ void routing_kernel(const int* __restrict__ idx, const float* __restrict__ w,
                               int* __restrict__ etk, float* __restrict__ ew,
                               int* __restrict__ cntpad) {
  __shared__ int cnt[NEXP];
  const int t = threadIdx.x;
  if (t < NEXP) cnt[t] = 0;
  __syncthreads();
  if (t < T_TOK) {
#pragma unroll
    for (int k = 0; k < TOPK; ++k) {
      int e = idx[t * TOPK + k];
      float wk = w[t * TOPK + k];
      int slot = atomicAdd(&cnt[e], 1);
      if (slot < CAP) { etk[e * CAP + slot] = (t << 2) | k; ew[e * CAP + slot] = wk; }
    }
  }
  __syncthreads();
  for (int e = 0; e < NEXP; ++e) {
    int c = cnt[e];
    int p = (c + 63) & ~63;
    if (p > CAP) p = CAP;
    for (int j = c + t; j < p; j += blockDim.x) {
      etk[e * CAP + j] = (T_TOK << 2);
      ew[e * CAP + j] = 0.f;
    }
    if (t == 0) cntpad[e] = p;
  }
}

__global__ void cvt_kernel(const float* __restrict__ src, bf16* __restrict__ dst, int n4) {
  int i = blockIdx.x * blockDim.x + threadIdx.x;
  if (i >= n4) return;
  float4 v = ((const float4*)src)[i];
  bf16x4 o;
  o[0] = (bf16)v.x; o[1] = (bf16)v.y; o[2] = (bf16)v.z; o[3] = (bf16)v.w;
  ((bf16x4*)dst)[i] = o;
}

// ---------------- GEMM1: hsc[entry,i] = silu(g)*u*w, g/u = hid[tok] . gup[e] ----------------
// tile 64(entries) x 64(I), BK=64, K=1024 (16 iters), double-buffered.
// A: bf16 async global->LDS (gathered rows). B: fp32 global->regs->cvt->LDS.
// LDS xor-swizzle: physical 16B chunk = logical ^ (row&7).

__global__ __launch_bounds__(256, 3) void gemm1_kernel(
    const bf16* __restrict__ hid,    // [(T+1),H] bf16, row T zeroed
    const float* __restrict__ gup,   // [E,2I,H] fp32
    const int* __restrict__ etk, const float* __restrict__ ew,
    const int* __restrict__ cntpad,
    bf16* __restrict__ hsc) {        // [E*CAP, I] bf16
  __shared__ __align__(16) bf16 As[2][64 * 64];
  __shared__ __align__(16) bf16 Bg[2][64 * 64];
  __shared__ __align__(16) bf16 Bu[2][64 * 64];
  const int e  = blockIdx.z;
  const int m0 = blockIdx.x * 64;
  if (m0 >= cntpad[e]) return;
  const int n0 = blockIdx.y * 64;
  const int ebase = e * CAP;
  const int tid  = threadIdx.x;
  const int lane = tid & 63;
  const int wid  = tid >> 6;
  const int wm = (wid >> 1) * 32;
  const int wn = (wid & 1) * 32;
  const int lcol  = lane & 15;
  const int lquad = lane >> 4;
  // A async staging: row srow (0..31), chunk tid&7, source col compensates swizzle
  const int srow = tid >> 3;
  const int swz  = ((tid & 7) ^ (srow & 7)) * 8;
  const int tokA0 = etk[ebase + m0 + srow] >> 2;
  const int tokA1 = etk[ebase + m0 + srow + 32] >> 2;
  const bf16* gA0 = hid + (size_t)tokA0 * HDIM + swz;
  const bf16* gA1 = hid + (size_t)tokA1 * HDIM + swz;
  // B fp32 staging: row br (0..63), cols c0..c0+15
  const int br = tid >> 2;
  const int c0 = (tid & 3) * 16;
  const float* gBg = gup + (size_t)e * (2 * IDIM) * HDIM + (size_t)(n0 + br) * HDIM + c0;
  const float* gBu = gBg + (size_t)IDIM * HDIM;
  const int wb0 = (((c0 >> 3) ^ (br & 7)) * 8);
  const int wb1 = ((((c0 >> 3) + 1) ^ (br & 7)) * 8);

  f32x4 accG[2][2], accU[2][2];
#pragma unroll
  for (int i = 0; i < 2; ++i)
#pragma unroll
    for (int j = 0; j < 2; ++j) {
      accG[i][j] = f32x4{0.f, 0.f, 0.f, 0.f};
      accU[i][j] = f32x4{0.f, 0.f, 0.f, 0.f};
    }

  float4 rg[4], ru[4];
  // prologue: stage iter 0 into buf 0
  lds_load16(&As[0][tid * 8], gA0);
  lds_load16(&As[0][tid * 8 + 2048], gA1);
#pragma unroll
  for (int j = 0; j < 4; ++j) {
    rg[j] = *(const float4*)(gBg + 4 * j);
    ru[j] = *(const float4*)(gBu + 4 * j);
  }
  *(bf16x8*)&Bg[0][br * 64 + wb0] = pack2(rg[0], rg[1]);
  *(bf16x8*)&Bg[0][br * 64 + wb1] = pack2(rg[2], rg[3]);
  *(bf16x8*)&Bu[0][br * 64 + wb0] = pack2(ru[0], ru[1]);
  *(bf16x8*)&Bu[0][br * 64 + wb1] = pack2(ru[2], ru[3]);

#pragma unroll 2
  for (int it = 0; it < 16; ++it) {
    const int cur = it & 1, nxt = cur ^ 1;
    __syncthreads();   // buf[cur] ready (vmcnt for async A, lgkm for B writes)
    if (it + 1 < 16) {
      const int ko = (it + 1) * 64;
      lds_load16(&As[nxt][tid * 8], gA0 + ko);
      lds_load16(&As[nxt][tid * 8 + 2048], gA1 + ko);
#pragma unroll
      for (int j = 0; j < 4; ++j) {
        rg[j] = *(const float4*)(gBg + ko + 4 * j);
        ru[j] = *(const float4*)(gBu + ko + 4 * j);
      }
    }
    // compute from buf[cur] while prefetch flies
#pragma unroll
    for (int ks = 0; ks < 2; ++ks) {
      bf16x8 af[2], bg[2], bu[2];
      const int lch = ks * 4 + lquad;
#pragma unroll
      for (int mf = 0; mf < 2; ++mf) {
        int row = wm + mf * 16 + lcol;
        af[mf] = *(const bf16x8*)&As[cur][row * 64 + ((lch ^ (row & 7)) * 8)];
      }
#pragma unroll
      for (int nf = 0; nf < 2; ++nf) {
        int row = wn + nf * 16 + lcol;
        int off = row * 64 + ((lch ^ (row & 7)) * 8);
        bg[nf] = *(const bf16x8*)&Bg[cur][off];
        bu[nf] = *(const bf16x8*)&Bu[cur][off];
      }
#pragma unroll
      for (int mf = 0; mf < 2; ++mf)
#pragma unroll
        for (int nf = 0; nf < 2; ++nf) {
          accG[mf][nf] = __builtin_amdgcn_mfma_f32_16x16x32_bf16(af[mf], bg[nf], accG[mf][nf], 0, 0, 0);
          accU[mf][nf] = __builtin_amdgcn_mfma_f32_16x16x32_bf16(af[mf], bu[nf], accU[mf][nf], 0, 0, 0);
        }
    }
    if (it + 1 < 16) {   // B reg->LDS after compute (waits its vmcnt here, post-overlap)
      *(bf16x8*)&Bg[nxt][br * 64 + wb0] = pack2(rg[0], rg[1]);
      *(bf16x8*)&Bg[nxt][br * 64 + wb1] = pack2(rg[2], rg[3]);
      *(bf16x8*)&Bu[nxt][br * 64 + wb0] = pack2(ru[0], ru[1]);
      *(bf16x8*)&Bu[nxt][br * 64 + wb1] = pack2(ru[2], ru[3]);
    }
  }
  // epilogue: C/D layout col=lane&15, row=lquad*4+reg
#pragma unroll
  for (int mf = 0; mf < 2; ++mf) {
#pragma unroll
    for (int rr = 0; rr < 4; ++rr) {
      const int erow = m0 + wm + mf * 16 + lquad * 4 + rr;
      const float wgt = ew[ebase + erow];
      bf16* orow = hsc + (size_t)(ebase + erow) * IDIM + n0 + wn;
#pragma unroll
      for (int nf = 0; nf < 2; ++nf) {
        float g = accG[mf][nf][rr];
        float u = accU[mf][nf][rr];
        float s = g / (1.f + __expf(-g));
        orow[nf * 16 + lcol] = (bf16)(s * u * wgt);
      }
    }
  }
}

// ---------------- GEMM2: slab[k][tok,h] = hsc[entry,:] . down[e,h,:] ----------------
// tile 64(entries) x 128(H), BK=64, K=512 (8 iters), double-buffered, plain stores.

__global__ __launch_bounds__(256, 3) void gemm2_kernel(
    const bf16* __restrict__ hsc,    // [E*CAP, I] bf16
    const float* __restrict__ down,  // [E,H,I] fp32
    const int* __restrict__ etk, const int* __restrict__ cntpad,
    float* __restrict__ slabs) {     // [4][(T+1)][H] fp32
  __shared__ __align__(16) bf16 As[2][64 * 64];
  __shared__ __align__(16) bf16 Bs[2][128 * 64];
  const int e  = blockIdx.z;
  const int m0 = blockIdx.x * 64;
  if (m0 >= cntpad[e]) return;
  const int n0 = blockIdx.y * 128;
  const int ebase = e * CAP;
  const int tid  = threadIdx.x;
  const int lane = tid & 63;
  const int wid  = tid >> 6;
  const int wm = (wid >> 1) * 32;
  const int wn = (wid & 1) * 64;
  const int lcol  = lane & 15;
  const int lquad = lane >> 4;
  const int srow = tid >> 3;
  const int swz  = ((tid & 7) ^ (srow & 7)) * 8;
  const bf16* gA = hsc + (size_t)(ebase + m0 + srow) * IDIM + swz;
  // B fp32: row br2 (0..127), cols c0..c0+31
  const int br2 = tid >> 1;
  const int c0  = (tid & 1) * 32;
  const float* gB = down + (size_t)e * HDIM * IDIM + (size_t)(n0 + br2) * IDIM + c0;
  int wb[4];
#pragma unroll
  for (int j = 0; j < 4; ++j) wb[j] = ((((c0 >> 3) + j) ^ (br2 & 7)) * 8);

  f32x4 acc[2][4];
#pragma unroll
  for (int i = 0; i < 2; ++i)
#pragma unroll
    for (int j = 0; j < 4; ++j) acc[i][j] = f32x4{0.f, 0.f, 0.f, 0.f};

  float4 rb[8];
  // prologue
  lds_load16(&As[0][tid * 8], gA);
  lds_load16(&As[0][tid * 8 + 2048], gA + (size_t)32 * IDIM);
#pragma unroll
  for (int j = 0; j < 8; ++j) rb[j] = *(const float4*)(gB + 4 * j);
#pragma unroll
  for (int j = 0; j < 4; ++j)
    *(bf16x8*)&Bs[0][br2 * 64 + wb[j]] = pack2(rb[2 * j], rb[2 * j + 1]);

#pragma unroll 2
  for (int it = 0; it < 8; ++it) {
    const int cur = it & 1, nxt = cur ^ 1;
    __syncthreads();
    if (it + 1 < 8) {
      const int ko = (it + 1) * 64;
      lds_load16(&As[nxt][tid * 8], gA + ko);
      lds_load16(&As[nxt][tid * 8 + 2048], gA + ko + (size_t)32 * IDIM);
#pragma unroll
      for (int j = 0; j < 8; ++j) rb[j] = *(const float4*)(gB + ko + 4 * j);
    }
#pragma unroll
    for (int ks = 0; ks < 2; ++ks) {
      bf16x8 af[2], bfv[4];
      const int lch = ks * 4 + lquad;
#pragma unroll
      for (int mf = 0; mf < 2; ++mf) {
        int row = wm + mf * 16 + lcol;
        af[mf] = *(const bf16x8*)&As[cur][row * 64 + ((lch ^ (row & 7)) * 8)];
      }
#pragma unroll
      for (int nf = 0; nf < 4; ++nf) {
        int row = wn + nf * 16 + lcol;
        bfv[nf] = *(const bf16x8*)&Bs[cur][row * 64 + ((lch ^ (row & 7)) * 8)];
      }
#pragma unroll
      for (int mf = 0; mf < 2; ++mf)
#pragma unroll
        for (int nf = 0; nf < 4; ++nf)
          acc[mf][nf] = __builtin_amdgcn_mfma_f32_16x16x32_bf16(af[mf], bfv[nf], acc[mf][nf], 0, 0, 0);
    }
    if (it + 1 < 8) {
#pragma unroll
      for (int j = 0; j < 4; ++j)
        *(bf16x8*)&Bs[nxt][br2 * 64 + wb[j]] = pack2(rb[2 * j], rb[2 * j + 1]);
    }
  }
  // epilogue: plain scatter-stores into per-slot slab
#pragma unroll
  for (int mf = 0; mf < 2; ++mf) {
#pragma unroll
    for (int rr = 0; rr < 4; ++rr) {
      const int erow = m0 + wm + mf * 16 + lquad * 4 + rr;
      const int tk = etk[ebase + erow];
      const int tok = tk >> 2, kslot = tk & 3;
      float* orow = slabs + ((size_t)kslot * (T_TOK + 1) + tok) * HDIM + n0 + wn;
#pragma unroll
      for (int nf = 0; nf < 4; ++nf)
        orow[nf * 16 + lcol] = acc[mf][nf][rr];
    }
  }
}

// ---------------- reduce: out = sum of 4 slabs ----------------

__global__ void reduce_kernel(const float* __restrict__ slabs, float* __restrict__ out) {
  const size_t stride = (size_t)(T_TOK + 1) * HDIM;
  int i = blockIdx.x * blockDim.x + threadIdx.x;   // float4 index over T*H
  float4 a = ((const float4*)slabs)[i];
  float4 b = ((const float4*)(slabs + stride))[i];
  float4 c = ((const float4*)(slabs + 2 * stride))[i];
  float4 d = ((const float4*)(slabs + 3 * stride))[i];
  float4 o;
  o.x = a.x + b.x + c.x + d.x;
  o.y = a.y + b.y + c.y + d.y;
  o.z = a.z + b.z + c.z + d.z;
  o.w = a.w + b.w + c.w + d.w;
  ((float4*)out)[i] = o;
}

// ---------------- launch ----------------

extern "C" void kernel_launch(void* const* d_in, const int* in_sizes, int n_in,
                              void* d_out, int out_size, void* d_ws, size_t ws_size,
                              hipStream_t stream) {
  const float* hid_f  = (const float*)d_in[0];
  const int*   idx    = (const int*)d_in[1];
  const float* tw     = (const float*)d_in[2];
  const float* gup_f  = (const float*)d_in[3];
  const float* down_f = (const float*)d_in[4];
  float* out = (float*)d_out;

  uint8_t* ws = (uint8_t*)d_ws;
  size_t off = 0;
  bf16* hid_b = (bf16*)(ws + off);   off += (size_t)(T_TOK + 1) * HDIM * 2;
  int*  etk   = (int*)(ws + off);    off += (size_t)NEXP * CAP * 4;
  float* ewt  = (float*)(ws + off);  off += (size_t)NEXP * CAP * 4;
  int* cntpad = (int*)(ws + off);    off += 256;
  bf16* hsc   = (bf16*)(ws + off);   off += (size_t)NEXP * CAP * IDIM * 2;
  float* slabs = (float*)(ws + off); // 4*(T+1)*H*4 = 16.8 MB

  routing_kernel<<<dim3(1), dim3(1024), 0, stream>>>(idx, tw, etk, ewt, cntpad);
  cvt_kernel<<<dim3(T_TOK * HDIM / 4 / 256), dim3(256), 0, stream>>>(hid_f, hid_b, T_TOK * HDIM / 4);
  hipMemsetAsync(hid_b + (size_t)T_TOK * HDIM, 0, HDIM * sizeof(bf16), stream);

  gemm1_kernel<<<dim3(CAP / 64, IDIM / 64, NEXP), dim3(256), 0, stream>>>(
      hid_b, gup_f, etk, ewt, cntpad, hsc);
  gemm2_kernel<<<dim3(CAP / 64, HDIM / 128, NEXP), dim3(256), 0, stream>>>(
      hsc, down_f, etk, cntpad, slabs);
  reduce_kernel<<<dim3(T_TOK * HDIM / 4 / 256), dim3(256), 0, stream>>>(slabs, out);
}

// Round 5
// 210.625 us; speedup vs baseline: 1.5110x; 1.5110x over previous
//
#include <hip/hip_runtime.h>
#include <hip/hip_bf16.h>
#include <cstdint>
#include <cstddef>

// Problem constants: T=1024, H=1024, I=512, E=16, K=4
#define T_TOK 1024
#define HDIM  1024
#define IDIM  512
#define NEXP  16
#define TOPK  4
#define CAP   1024   // per-expert entry capacity (mean 256, sd ~15.5)

typedef __bf16 bf16;
typedef __attribute__((ext_vector_type(8))) __bf16 bf16x8;
typedef __attribute__((ext_vector_type(4))) __bf16 bf16x4;
typedef __attribute__((ext_vector_type(4))) float f32x4;

__device__ __forceinline__ void lds_load16(void* lds_dst, const void* g_src) {
  __builtin_amdgcn_global_load_lds(
      (__attribute__((address_space(1))) unsigned int*)(void*)(g_src),
      (__attribute__((address_space(3))) unsigned int*)(lds_dst),
      16, 0, 0);
}

__device__ __forceinline__ bf16x4 cvt4(float4 a) {
  bf16x4 o;
  o[0] = (bf16)a.x; o[1] = (bf16)a.y; o[2] = (bf16)a.z; o[3] = (bf16)a.w;
  return o;
}
__device__ __forceinline__ bf16x8 pack2(float4 a, float4 b) {
  bf16x8 o;
  o[0] = (bf16)a.x; o[1] = (bf16)a.y; o[2] = (bf16)a.z; o[3] = (bf16)a.w;
  o[4] = (bf16)b.x; o[5] = (bf16)b.y; o[6] = (bf16)b.z; o[7] = (bf16)b.w;
  return o;
}

// ---------------- prep ----------------

// 16 blocks, one per expert: scan all (t,k), collect matches. Payload (t<<2)|k.
// Pads to x64 with token T_TOK (zero gather row / trash scatter row), weight 0.
__global__ void routing_kernel(const int* __restrict__ idx, const float* __restrict__ w,
                               int* __restrict__ etk, float* __restrict__ ew,
                               int* __restrict__ cntpad) {
  __shared__ int cnt;
  const int e = blockIdx.x;
  const int tid = threadIdx.x;
  if (tid == 0) cnt = 0;
  __syncthreads();
  for (int j = tid; j < T_TOK * TOPK; j += blockDim.x) {
    if (idx[j] == e) {
      int slot = atomicAdd(&cnt, 1);
      if (slot < CAP) { etk[e * CAP + slot] = j; ew[e * CAP + slot] = w[j]; }
    }
  }
  __syncthreads();
  int c = cnt < CAP ? cnt : CAP;
  int p = (c + 63) & ~63;
  for (int j = c + tid; j < p; j += blockDim.x) {
    etk[e * CAP + j] = (T_TOK << 2);
    ew[e * CAP + j] = 0.f;
  }
  if (tid == 0) cntpad[e] = p;
}

__global__ void cvt_kernel(const float* __restrict__ src, bf16* __restrict__ dst, int n4) {
  int i = blockIdx.x * blockDim.x + threadIdx.x;
  if (i >= n4) return;
  float4 v = ((const float4*)src)[i];
  ((bf16x4*)dst)[i] = cvt4(v);
}

// ---------------- GEMM1: hsc[entry, i] = silu(g)*u*wgt ----------------
// Block owns (e, 16 I-channels). B slice (16 gate + 16 up rows x K=1024 fp32, 128 KB)
// read from HBM on m=0, L2 on m>=1. m-loop over 64-entry tiles, 512 all-active blocks.
// Single-buffered 2-barrier K-loop (proven structure). LDS xor-swizzle (chunk ^= row&7).

__global__ __launch_bounds__(256, 2) void gemm1_kernel(
    const bf16* __restrict__ hid,    // [(T+1),H] bf16, row T zeroed
    const float* __restrict__ gup,   // [E,2I,H] fp32
    const int* __restrict__ etk, const float* __restrict__ ew,
    const int* __restrict__ cntpad,
    bf16* __restrict__ hsc) {        // [E*CAP, I] bf16
  __shared__ __align__(16) bf16 As[64 * 64];
  __shared__ __align__(16) bf16 BgS[16 * 64];
  __shared__ __align__(16) bf16 BuS[16 * 64];
  const int e  = blockIdx.y;
  const int trips = cntpad[e] >> 6;
  const int n0 = blockIdx.x * 16;
  const int ebase = e * CAP;
  const int tid = threadIdx.x, lane = tid & 63, wid = tid >> 6;
  const int wm = wid * 16;               // wave's 16 entry-rows
  const int lcol = lane & 15, lquad = lane >> 4;
  // A async staging: row srow (0..31) (+32 for 2nd), src col compensates swizzle
  const int srow = tid >> 3;
  const int swz  = ((tid & 7) ^ (srow & 7)) * 8;
  // B staging: 16 rows, br=tid>>4, bc=(tid&15)*4 elems; half-chunk writes
  const int br = tid >> 4;
  const int bc = (tid & 15) * 4;
  const int wb = (((bc >> 3) ^ (br & 7)) * 8) + (bc & 7);
  const float* gBg = gup + (size_t)e * (2 * IDIM) * HDIM + (size_t)(n0 + br) * HDIM + bc;
  const float* gBu = gBg + (size_t)IDIM * HDIM;

  for (int m = 0; m < trips; ++m) {
    const int mb = ebase + m * 64;
    const int t0 = etk[mb + srow] >> 2;
    const int t1 = etk[mb + srow + 32] >> 2;
    const bf16* gA0 = hid + (size_t)t0 * HDIM + swz;
    const bf16* gA1 = hid + (size_t)t1 * HDIM + swz;
    f32x4 aG = f32x4{0.f, 0.f, 0.f, 0.f};
    f32x4 aU = f32x4{0.f, 0.f, 0.f, 0.f};
    for (int k = 0; k < 16; ++k) {
      float4 vg = *(const float4*)(gBg + k * 64);   // reg-only, before barrier
      float4 vu = *(const float4*)(gBu + k * 64);
      __syncthreads();                              // prev compute done
      lds_load16(&As[tid * 8],        gA0 + k * 64);
      lds_load16(&As[tid * 8 + 2048], gA1 + k * 64);
      *(bf16x4*)&BgS[br * 64 + wb] = cvt4(vg);
      *(bf16x4*)&BuS[br * 64 + wb] = cvt4(vu);
      __syncthreads();                              // staging visible (vmcnt drained)
#pragma unroll
      for (int ks = 0; ks < 2; ++ks) {
        const int lch = ks * 4 + lquad;
        const int arow = wm + lcol;
        bf16x8 af = *(const bf16x8*)&As[arow * 64 + ((lch ^ (arow & 7)) * 8)];
        bf16x8 bg = *(const bf16x8*)&BgS[lcol * 64 + ((lch ^ (lcol & 7)) * 8)];
        bf16x8 bu = *(const bf16x8*)&BuS[lcol * 64 + ((lch ^ (lcol & 7)) * 8)];
        aG = __builtin_amdgcn_mfma_f32_16x16x32_bf16(af, bg, aG, 0, 0, 0);
        aU = __builtin_amdgcn_mfma_f32_16x16x32_bf16(af, bu, aU, 0, 0, 0);
      }
    }
    // epilogue: C/D layout col=lane&15, row=lquad*4+reg
#pragma unroll
    for (int rr = 0; rr < 4; ++rr) {
      const int erow = m * 64 + wm + lquad * 4 + rr;
      const float wgt = ew[ebase + erow];
      float g = aG[rr], u = aU[rr];
      float s = g / (1.f + __expf(-g));
      hsc[(size_t)(ebase + erow) * IDIM + n0 + lcol] = (bf16)(s * u * wgt);
    }
  }
}

// ---------------- GEMM2: slab[k][tok,h] = hsc[entry,:] . down[e,h,:] ----------------
// Block owns (e, 32 H-channels). B slice (32 rows x K=512 fp32, 64 KB) HBM once.
// m-loop over 64-entry tiles, 512 all-active blocks, plain scatter stores to slabs.

__global__ __launch_bounds__(256, 2) void gemm2_kernel(
    const bf16* __restrict__ hsc,    // [E*CAP, I] bf16
    const float* __restrict__ down,  // [E,H,I] fp32
    const int* __restrict__ etk, const int* __restrict__ cntpad,
    float* __restrict__ slabs) {     // [4][(T+1)][H] fp32
  __shared__ __align__(16) bf16 As[64 * 64];
  __shared__ __align__(16) bf16 Bs[32 * 64];
  const int e  = blockIdx.y;
  const int trips = cntpad[e] >> 6;
  const int n0 = blockIdx.x * 32;
  const int ebase = e * CAP;
  const int tid = threadIdx.x, lane = tid & 63, wid = tid >> 6;
  const int wm = wid * 16;
  const int lcol = lane & 15, lquad = lane >> 4;
  const int srow = tid >> 3;
  const int swz  = ((tid & 7) ^ (srow & 7)) * 8;
  // B staging: 32 rows, btr=tid>>3, c0=(tid&7)*8 elems; full-chunk writes
  const int btr = tid >> 3;
  const int c0  = (tid & 7) * 8;
  const int wbk = (((tid & 7) ^ (btr & 7)) * 8);
  const float* gB = down + (size_t)e * HDIM * IDIM + (size_t)(n0 + btr) * IDIM + c0;

  for (int m = 0; m < trips; ++m) {
    const int mb = ebase + m * 64;
    int tks[4];
#pragma unroll
    for (int rr = 0; rr < 4; ++rr) tks[rr] = etk[mb + wm + lquad * 4 + rr];
    const bf16* gA = hsc + (size_t)(mb + srow) * IDIM + swz;
    f32x4 acc0 = f32x4{0.f, 0.f, 0.f, 0.f};
    f32x4 acc1 = f32x4{0.f, 0.f, 0.f, 0.f};
    for (int k = 0; k < 8; ++k) {
      float4 v0 = *(const float4*)(gB + k * 64);
      float4 v1 = *(const float4*)(gB + k * 64 + 4);
      __syncthreads();
      lds_load16(&As[tid * 8],        gA + k * 64);
      lds_load16(&As[tid * 8 + 2048], gA + k * 64 + (size_t)32 * IDIM);
      *(bf16x8*)&Bs[btr * 64 + wbk] = pack2(v0, v1);
      __syncthreads();
#pragma unroll
      for (int ks = 0; ks < 2; ++ks) {
        const int lch = ks * 4 + lquad;
        const int arow = wm + lcol;
        bf16x8 af = *(const bf16x8*)&As[arow * 64 + ((lch ^ (arow & 7)) * 8)];
#pragma unroll
        for (int nf = 0; nf < 2; ++nf) {
          const int brow = nf * 16 + lcol;
          bf16x8 bv = *(const bf16x8*)&Bs[brow * 64 + ((lch ^ (brow & 7)) * 8)];
          if (nf == 0) acc0 = __builtin_amdgcn_mfma_f32_16x16x32_bf16(af, bv, acc0, 0, 0, 0);
          else         acc1 = __builtin_amdgcn_mfma_f32_16x16x32_bf16(af, bv, acc1, 0, 0, 0);
        }
      }
    }
    // epilogue: plain scatter stores (each (t,k) slab row written once)
#pragma unroll
    for (int rr = 0; rr < 4; ++rr) {
      const int tok = tks[rr] >> 2, kslot = tks[rr] & 3;
      float* orow = slabs + ((size_t)kslot * (T_TOK + 1) + tok) * HDIM + n0;
      orow[lcol]      = acc0[rr];
      orow[16 + lcol] = acc1[rr];
    }
  }
}

// ---------------- reduce: out = sum of 4 slabs ----------------

__global__ void reduce_kernel(const float* __restrict__ slabs, float* __restrict__ out) {
  const size_t stride = (size_t)(T_TOK + 1) * HDIM;
  int i = blockIdx.x * blockDim.x + threadIdx.x;
  float4 a = ((const float4*)slabs)[i];
  float4 b = ((const float4*)(slabs + stride))[i];
  float4 c = ((const float4*)(slabs + 2 * stride))[i];
  float4 d = ((const float4*)(slabs + 3 * stride))[i];
  float4 o;
  o.x = a.x + b.x + c.x + d.x;
  o.y = a.y + b.y + c.y + d.y;
  o.z = a.z + b.z + c.z + d.z;
  o.w = a.w + b.w + c.w + d.w;
  ((float4*)out)[i] = o;
}

// ---------------- launch ----------------

extern "C" void kernel_launch(void* const* d_in, const int* in_sizes, int n_in,
                              void* d_out, int out_size, void* d_ws, size_t ws_size,
                              hipStream_t stream) {
  const float* hid_f  = (const float*)d_in[0];
  const int*   idx    = (const int*)d_in[1];
  const float* tw     = (const float*)d_in[2];
  const float* gup_f  = (const float*)d_in[3];
  const float* down_f = (const float*)d_in[4];
  float* out = (float*)d_out;

  uint8_t* ws = (uint8_t*)d_ws;
  size_t off = 0;
  bf16* hid_b = (bf16*)(ws + off);   off += (size_t)(T_TOK + 1) * HDIM * 2;
  int*  etk   = (int*)(ws + off);    off += (size_t)NEXP * CAP * 4;
  float* ewt  = (float*)(ws + off);  off += (size_t)NEXP * CAP * 4;
  int* cntpad = (int*)(ws + off);    off += 256;
  bf16* hsc   = (bf16*)(ws + off);   off += (size_t)NEXP * CAP * IDIM * 2;
  float* slabs = (float*)(ws + off); // 4*(T+1)*H*4 ≈ 16.8 MB

  routing_kernel<<<dim3(NEXP), dim3(256), 0, stream>>>(idx, tw, etk, ewt, cntpad);
  cvt_kernel<<<dim3(T_TOK * HDIM / 4 / 256), dim3(256), 0, stream>>>(hid_f, hid_b, T_TOK * HDIM / 4);
  hipMemsetAsync(hid_b + (size_t)T_TOK * HDIM, 0, HDIM * sizeof(bf16), stream);

  gemm1_kernel<<<dim3(IDIM / 16, NEXP), dim3(256), 0, stream>>>(
      hid_b, gup_f, etk, ewt, cntpad, hsc);
  gemm2_kernel<<<dim3(HDIM / 32, NEXP), dim3(256), 0, stream>>>(
      hsc, down_f, etk, cntpad, slabs);
  reduce_kernel<<<dim3(T_TOK * HDIM / 4 / 256), dim3(256), 0, stream>>>(slabs, out);
}

// Round 6
// 207.374 us; speedup vs baseline: 1.5347x; 1.0157x over previous
//
#include <hip/hip_runtime.h>
#include <hip/hip_bf16.h>
#include <cstdint>
#include <cstddef>

// Problem constants: T=1024, H=1024, I=512, E=16, K=4
#define T_TOK 1024
#define HDIM  1024
#define IDIM  512
#define NEXP  16
#define TOPK  4
#define CAP   1024   // per-expert entry capacity (mean 256, sd ~15.5)

typedef __bf16 bf16;
typedef __attribute__((ext_vector_type(8))) __bf16 bf16x8;
typedef __attribute__((ext_vector_type(4))) __bf16 bf16x4;
typedef __attribute__((ext_vector_type(4))) float f32x4;

__device__ __forceinline__ void lds_load16(void* lds_dst, const void* g_src) {
  __builtin_amdgcn_global_load_lds(
      (__attribute__((address_space(1))) unsigned int*)(void*)(g_src),
      (__attribute__((address_space(3))) unsigned int*)(lds_dst),
      16, 0, 0);
}

__device__ __forceinline__ bf16x4 cvt4(float4 a) {
  bf16x4 o;
  o[0] = (bf16)a.x; o[1] = (bf16)a.y; o[2] = (bf16)a.z; o[3] = (bf16)a.w;
  return o;
}
__device__ __forceinline__ bf16x8 pack2(float4 a, float4 b) {
  bf16x8 o;
  o[0] = (bf16)a.x; o[1] = (bf16)a.y; o[2] = (bf16)a.z; o[3] = (bf16)a.w;
  o[4] = (bf16)b.x; o[5] = (bf16)b.y; o[6] = (bf16)b.z; o[7] = (bf16)b.w;
  return o;
}

// ---------------- fused prep: cvt hid->bf16 (+zero row T) and routing ----------------
// blocks [0,1024): cvt; blocks [1024,1040): routing for expert b-1024.

#define CVT_BLOCKS (T_TOK * HDIM / 4 / 256)   // 1024

__global__ void prep_kernel(const float* __restrict__ hid_f, bf16* __restrict__ hid_b,
                            const int* __restrict__ idx, const float* __restrict__ w,
                            int* __restrict__ etk, float* __restrict__ ew,
                            int* __restrict__ cntpad) {
  __shared__ int cnt;
  const int b = blockIdx.x;
  const int tid = threadIdx.x;
  if (b < CVT_BLOCKS) {
    int i = b * 256 + tid;
    float4 v = ((const float4*)hid_f)[i];
    ((bf16x4*)hid_b)[i] = cvt4(v);
    if (b == 0)  // zero pad row T (HDIM bf16 = 256 x bf16x4)
      ((bf16x4*)(hid_b + (size_t)T_TOK * HDIM))[tid] = cvt4(make_float4(0.f, 0.f, 0.f, 0.f));
    return;
  }
  // routing (proven R5 body), one block per expert
  const int e = b - CVT_BLOCKS;
  if (tid == 0) cnt = 0;
  __syncthreads();
  for (int j = tid; j < T_TOK * TOPK; j += blockDim.x) {
    if (idx[j] == e) {
      int slot = atomicAdd(&cnt, 1);
      if (slot < CAP) { etk[e * CAP + slot] = j; ew[e * CAP + slot] = w[j]; }
    }
  }
  __syncthreads();
  int c = cnt < CAP ? cnt : CAP;
  int p = (c + 63) & ~63;
  for (int j = c + tid; j < p; j += blockDim.x) {
    etk[e * CAP + j] = (T_TOK << 2);
    ew[e * CAP + j] = 0.f;
  }
  if (tid == 0) cntpad[e] = p;
}

// ---------------- GEMM1: hsc[entry, i] = silu(g)*u*wgt ----------------
// Block owns (e, 16 I-channels, m-parity z). BK=128, dbuf LDS, 2-barrier loop.
// Grid (32, 16, 2) = 1024 all-active blocks. LDS 48KB -> 3 blocks/CU.
// Swizzle: 16B chunk c of row r stored at chunk c^(r&7).

__global__ __launch_bounds__(256, 3) void gemm1_kernel(
    const bf16* __restrict__ hid,    // [(T+1),H] bf16, row T zeroed
    const float* __restrict__ gup,   // [E,2I,H] fp32
    const int* __restrict__ etk, const float* __restrict__ ew,
    const int* __restrict__ cntpad,
    bf16* __restrict__ hsc) {        // [E*CAP, I] bf16
  __shared__ __align__(16) bf16 As[2][64 * 128];   // 2x16KB
  __shared__ __align__(16) bf16 BgS[2][16 * 128];  // 2x4KB
  __shared__ __align__(16) bf16 BuS[2][16 * 128];  // 2x4KB
  const int e  = blockIdx.y;
  const int z  = blockIdx.z;
  const int trips = cntpad[e] >> 6;
  const int n0 = blockIdx.x * 16;
  const int ebase = e * CAP;
  const int tid = threadIdx.x, lane = tid & 63, wid = tid >> 6;
  const int wm = wid * 16;
  const int lcol = lane & 15, lquad = lane >> 4;
  // A async staging: thread writes 4 chunks, rows (tid>>4)+16i, phys chunk tid&15
  const int arow0 = tid >> 4;                           // 0..15
  const int swzA  = (((tid & 15) ^ (arow0 & 7)) * 8);   // src elem offset (logical chunk)
  // B staging: row br (0..15), 8 fp32 elems at bc; full-chunk bf16x8 writes
  const int br = tid >> 4;
  const int bc = (tid & 15) * 8;
  const int physB = ((tid & 15) ^ (br & 7)) * 8;
  const float* gBg = gup + (size_t)e * (2 * IDIM) * HDIM + (size_t)(n0 + br) * HDIM + bc;
  const float* gBu = gBg + (size_t)IDIM * HDIM;

  for (int m = z; m < trips; m += 2) {
    const int mb = ebase + m * 64;
    const bf16* gA[4];
#pragma unroll
    for (int i = 0; i < 4; ++i) {
      int t = etk[mb + arow0 + 16 * i] >> 2;
      gA[i] = hid + (size_t)t * HDIM + swzA;
    }
    float wgt[4];
#pragma unroll
    for (int rr = 0; rr < 4; ++rr) wgt[rr] = ew[mb + wm + lquad * 4 + rr];

    f32x4 aG = f32x4{0.f, 0.f, 0.f, 0.f};
    f32x4 aU = f32x4{0.f, 0.f, 0.f, 0.f};

    // prologue: stage k=0 into buf0 (buf0 reads of prev trip finished pre its last barrier)
#pragma unroll
    for (int i = 0; i < 4; ++i) lds_load16(&As[0][tid * 8 + i * 2048], gA[i]);
    {
      float4 g0 = *(const float4*)(gBg), g1 = *(const float4*)(gBg + 4);
      float4 u0 = *(const float4*)(gBu), u1 = *(const float4*)(gBu + 4);
      *(bf16x8*)&BgS[0][br * 128 + physB] = pack2(g0, g1);
      *(bf16x8*)&BuS[0][br * 128 + physB] = pack2(u0, u1);
    }
#pragma unroll 2
    for (int k = 0; k < 8; ++k) {
      const int cur = k & 1, nxt = cur ^ 1;
      __syncthreads();   // buf[cur] staged & visible
      float4 g0, g1, u0, u1;
      if (k < 7) {       // prefetch k+1 into buf[nxt]
        const int ko = (k + 1) * 128;
#pragma unroll
        for (int i = 0; i < 4; ++i) lds_load16(&As[nxt][tid * 8 + i * 2048], gA[i] + ko);
        g0 = *(const float4*)(gBg + ko); g1 = *(const float4*)(gBg + ko + 4);
        u0 = *(const float4*)(gBu + ko); u1 = *(const float4*)(gBu + ko + 4);
      }
      // compute buf[cur]: 4 k-steps x (gate, up)
#pragma unroll
      for (int ks = 0; ks < 4; ++ks) {
        const int lch = ks * 4 + lquad;
        const int ar = wm + lcol;
        bf16x8 af = *(const bf16x8*)&As[cur][ar * 128 + ((lch ^ (ar & 7)) * 8)];
        bf16x8 bg = *(const bf16x8*)&BgS[cur][lcol * 128 + ((lch ^ (lcol & 7)) * 8)];
        bf16x8 bu = *(const bf16x8*)&BuS[cur][lcol * 128 + ((lch ^ (lcol & 7)) * 8)];
        aG = __builtin_amdgcn_mfma_f32_16x16x32_bf16(af, bg, aG, 0, 0, 0);
        aU = __builtin_amdgcn_mfma_f32_16x16x32_bf16(af, bu, aU, 0, 0, 0);
      }
      if (k < 7) {
        *(bf16x8*)&BgS[nxt][br * 128 + physB] = pack2(g0, g1);
        *(bf16x8*)&BuS[nxt][br * 128 + physB] = pack2(u0, u1);
      }
    }
    // epilogue: C/D col=lane&15, row=lquad*4+rr
#pragma unroll
    for (int rr = 0; rr < 4; ++rr) {
      const int erow = m * 64 + wm + lquad * 4 + rr;
      float g = aG[rr], u = aU[rr];
      float s = g / (1.f + __expf(-g));
      hsc[(size_t)(ebase + erow) * IDIM + n0 + lcol] = (bf16)(s * u * wgt[rr]);
    }
  }
}

// ---------------- GEMM2: slab[k][tok,h] = hsc[entry,:] . down[e,h,:] ----------------
// Block owns (e, 32 H-channels, m-parity z). BK=128, dbuf, K=512 -> 4 iters/trip.
// Grid (32, 16, 2) = 1024 blocks, 48KB LDS -> 3 blocks/CU. Plain scatter stores.

__global__ __launch_bounds__(256, 3) void gemm2_kernel(
    const bf16* __restrict__ hsc,    // [E*CAP, I] bf16
    const float* __restrict__ down,  // [E,H,I] fp32
    const int* __restrict__ etk, const int* __restrict__ cntpad,
    float* __restrict__ slabs) {     // [4][(T+1)][H] fp32
  __shared__ __align__(16) bf16 As[2][64 * 128];   // 2x16KB
  __shared__ __align__(16) bf16 Bs[2][32 * 128];   // 2x8KB
  const int e  = blockIdx.y;
  const int z  = blockIdx.z;
  const int trips = cntpad[e] >> 6;
  const int n0 = blockIdx.x * 32;
  const int ebase = e * CAP;
  const int tid = threadIdx.x, lane = tid & 63, wid = tid >> 6;
  const int wm = wid * 16;
  const int lcol = lane & 15, lquad = lane >> 4;
  const int arow0 = tid >> 4;
  const int swzA  = (((tid & 15) ^ (arow0 & 7)) * 8);
  // B staging: row btr (0..31), 16 fp32 elems at bc; two chunk writes
  const int btr = tid >> 3;
  const int bc  = (tid & 7) * 16;
  const int cb0 = (tid & 7) * 2;
  const int physB0 = (cb0 ^ (btr & 7)) * 8;
  const int physB1 = ((cb0 + 1) ^ (btr & 7)) * 8;
  const float* gB = down + (size_t)e * HDIM * IDIM + (size_t)(n0 + btr) * IDIM + bc;

  for (int m = z; m < trips; m += 2) {
    const int mb = ebase + m * 64;
    const bf16* gA[4];
#pragma unroll
    for (int i = 0; i < 4; ++i)
      gA[i] = hsc + (size_t)(mb + arow0 + 16 * i) * IDIM + swzA;
    int tks[4];
#pragma unroll
    for (int rr = 0; rr < 4; ++rr) tks[rr] = etk[mb + wm + lquad * 4 + rr];

    f32x4 acc0 = f32x4{0.f, 0.f, 0.f, 0.f};
    f32x4 acc1 = f32x4{0.f, 0.f, 0.f, 0.f};

#pragma unroll
    for (int i = 0; i < 4; ++i) lds_load16(&As[0][tid * 8 + i * 2048], gA[i]);
    {
      float4 v0 = *(const float4*)(gB),     v1 = *(const float4*)(gB + 4);
      float4 v2 = *(const float4*)(gB + 8), v3 = *(const float4*)(gB + 12);
      *(bf16x8*)&Bs[0][btr * 128 + physB0] = pack2(v0, v1);
      *(bf16x8*)&Bs[0][btr * 128 + physB1] = pack2(v2, v3);
    }
#pragma unroll 2
    for (int k = 0; k < 4; ++k) {
      const int cur = k & 1, nxt = cur ^ 1;
      __syncthreads();
      float4 v0, v1, v2, v3;
      if (k < 3) {
        const int ko = (k + 1) * 128;
#pragma unroll
        for (int i = 0; i < 4; ++i) lds_load16(&As[nxt][tid * 8 + i * 2048], gA[i] + ko);
        v0 = *(const float4*)(gB + ko);     v1 = *(const float4*)(gB + ko + 4);
        v2 = *(const float4*)(gB + ko + 8); v3 = *(const float4*)(gB + ko + 12);
      }
#pragma unroll
      for (int ks = 0; ks < 4; ++ks) {
        const int lch = ks * 4 + lquad;
        const int ar = wm + lcol;
        bf16x8 af = *(const bf16x8*)&As[cur][ar * 128 + ((lch ^ (ar & 7)) * 8)];
        const int br0 = lcol, br1 = 16 + lcol;
        bf16x8 b0 = *(const bf16x8*)&Bs[cur][br0 * 128 + ((lch ^ (br0 & 7)) * 8)];
        bf16x8 b1 = *(const bf16x8*)&Bs[cur][br1 * 128 + ((lch ^ (br1 & 7)) * 8)];
        acc0 = __builtin_amdgcn_mfma_f32_16x16x32_bf16(af, b0, acc0, 0, 0, 0);
        acc1 = __builtin_amdgcn_mfma_f32_16x16x32_bf16(af, b1, acc1, 0, 0, 0);
      }
      if (k < 3) {
        *(bf16x8*)&Bs[nxt][btr * 128 + physB0] = pack2(v0, v1);
        *(bf16x8*)&Bs[nxt][btr * 128 + physB1] = pack2(v2, v3);
      }
    }
    // epilogue: plain scatter stores (each (t,k) slab row written once)
#pragma unroll
    for (int rr = 0; rr < 4; ++rr) {
      const int tok = tks[rr] >> 2, kslot = tks[rr] & 3;
      float* orow = slabs + ((size_t)kslot * (T_TOK + 1) + tok) * HDIM + n0;
      orow[lcol]      = acc0[rr];
      orow[16 + lcol] = acc1[rr];
    }
  }
}

// ---------------- reduce: out = sum of 4 slabs ----------------

__global__ void reduce_kernel(const float* __restrict__ slabs, float* __restrict__ out) {
  const size_t stride = (size_t)(T_TOK + 1) * HDIM;
  int i = blockIdx.x * blockDim.x + threadIdx.x;
  float4 a = ((const float4*)slabs)[i];
  float4 b = ((const float4*)(slabs + stride))[i];
  float4 c = ((const float4*)(slabs + 2 * stride))[i];
  float4 d = ((const float4*)(slabs + 3 * stride))[i];
  float4 o;
  o.x = a.x + b.x + c.x + d.x;
  o.y = a.y + b.y + c.y + d.y;
  o.z = a.z + b.z + c.z + d.z;
  o.w = a.w + b.w + c.w + d.w;
  ((float4*)out)[i] = o;
}

// ---------------- launch ----------------

extern "C" void kernel_launch(void* const* d_in, const int* in_sizes, int n_in,
                              void* d_out, int out_size, void* d_ws, size_t ws_size,
                              hipStream_t stream) {
  const float* hid_f  = (const float*)d_in[0];
  const int*   idx    = (const int*)d_in[1];
  const float* tw     = (const float*)d_in[2];
  const float* gup_f  = (const float*)d_in[3];
  const float* down_f = (const float*)d_in[4];
  float* out = (float*)d_out;

  uint8_t* ws = (uint8_t*)d_ws;
  size_t off = 0;
  bf16* hid_b = (bf16*)(ws + off);   off += (size_t)(T_TOK + 1) * HDIM * 2;
  int*  etk   = (int*)(ws + off);    off += (size_t)NEXP * CAP * 4;
  float* ewt  = (float*)(ws + off);  off += (size_t)NEXP * CAP * 4;
  int* cntpad = (int*)(ws + off);    off += 256;
  bf16* hsc   = (bf16*)(ws + off);   off += (size_t)NEXP * CAP * IDIM * 2;
  float* slabs = (float*)(ws + off); // 4*(T+1)*H*4 ≈ 16.8 MB

  prep_kernel<<<dim3(CVT_BLOCKS + NEXP), dim3(256), 0, stream>>>(
      hid_f, hid_b, idx, tw, etk, ewt, cntpad);
  gemm1_kernel<<<dim3(IDIM / 16, NEXP, 2), dim3(256), 0, stream>>>(
      hid_b, gup_f, etk, ewt, cntpad, hsc);
  gemm2_kernel<<<dim3(HDIM / 32, NEXP, 2), dim3(256), 0, stream>>>(
      hsc, down_f, etk, cntpad, slabs);
  reduce_kernel<<<dim3(T_TOK * HDIM / 4 / 256), dim3(256), 0, stream>>>(slabs, out);
}